// Round 8
// baseline (109.707 us; speedup 1.0000x reference)
//
#include <hip/hip_runtime.h>
#include <hip/hip_bf16.h>

#define B_ROWS 4096
#define NROWS  8192   // 2B
#define D      256
#define NSEG   48     // segments per strip-pair
#define NBLK2  768    // 16 pairs * 48 segments  (= 3 blocks/CU)
#define TT     264    // 32-col tiles per strip-pair

typedef __attribute__((ext_vector_type(4))) float floatx4;

// ---------------------------------------------------------------------------
// Kernel 1: normalize -> fp8 e4m3 z (2 MiB), exact fp32 pos, zero-inits.
// Diagonal handled by predicate in the GEMM epilogue -> no selfdot needed.
// ---------------------------------------------------------------------------
__global__ __launch_bounds__(256) void norm_pos_kernel(
    const float* __restrict__ xi, const float* __restrict__ xj,
    unsigned char* __restrict__ z, float* __restrict__ pos,
    float* __restrict__ rowsum, float* __restrict__ out,
    unsigned int* __restrict__ counter) {
    int gt = blockIdx.x * 256 + threadIdx.x;
    if (gt < NROWS) rowsum[gt] = 0.f;
    if (gt == 0) { out[0] = 0.f; counter[0] = 0u; }

    int p    = blockIdx.x * 4 + (threadIdx.x >> 6);
    int lane = threadIdx.x & 63;
    float4 v1 = ((const float4*)(xi + (size_t)p * D))[lane];
    float4 v2 = ((const float4*)(xj + (size_t)p * D))[lane];
    float ss1 = v1.x * v1.x + v1.y * v1.y + v1.z * v1.z + v1.w * v1.w;
    float ss2 = v2.x * v2.x + v2.y * v2.y + v2.z * v2.z + v2.w * v2.w;
#pragma unroll
    for (int off = 32; off > 0; off >>= 1) {
        ss1 += __shfl_xor(ss1, off);
        ss2 += __shfl_xor(ss2, off);
    }
    float sc1 = 1.0f / fmaxf(sqrtf(ss1), 1e-12f);
    float sc2 = 1.0f / fmaxf(sqrtf(ss2), 1e-12f);

    float n1x = v1.x * sc1, n1y = v1.y * sc1, n1z = v1.z * sc1, n1w = v1.w * sc1;
    float n2x = v2.x * sc2, n2y = v2.y * sc2, n2z = v2.z * sc2, n2w = v2.w * sc2;

    // exact fp32 positive-pair dot (pre-quantization)
    float dp = n1x * n2x + n1y * n2y + n1z * n2z + n1w * n2w;
#pragma unroll
    for (int off = 32; off > 0; off >>= 1) dp += __shfl_xor(dp, off);
    if (lane == 0) { pos[p] = dp; pos[p + B_ROWS] = dp; }

    // quantize to OCP e4m3: byte j = element k = lane*4 + j
    int q1 = __builtin_amdgcn_cvt_pk_fp8_f32(n1x, n1y, 0, false);
    q1     = __builtin_amdgcn_cvt_pk_fp8_f32(n1z, n1w, q1, true);
    int q2 = __builtin_amdgcn_cvt_pk_fp8_f32(n2x, n2y, 0, false);
    q2     = __builtin_amdgcn_cvt_pk_fp8_f32(n2z, n2w, q2, true);
    ((int*)(z + (size_t)p * D))[lane]            = q1;
    ((int*)(z + (size_t)(p + B_ROWS) * D))[lane] = q2;
}

// ---------------------------------------------------------------------------
// Kernel 2: symmetric sim+exp+rowsum, fp8 MFMA, register-resident A panels.
// Strip-pair s: panel s with panel 31-s; 264 32-col tiles over 48 segments.
// Wave A-panel: 64 rows x 256 K fp8 = 64 VGPRs (a[kk][mi] as i64).
// B tile: 32 cols x 256 K = 8 KB, double-buffered LDS, chunk-transposed
// [c16][col] in 16B units (phase-balanced b64 reads / b128 writes).
// Diag-region tiles (cloc<8) predicate out row==col; mirror tiles (cloc>=8)
// also add col-sums to the transposed rows.
// ---------------------------------------------------------------------------
__global__ __launch_bounds__(256, 3) void sim_rowsum_kernel(
    const unsigned char* __restrict__ z, float* __restrict__ rowsum,
    const float* __restrict__ pos, unsigned int* __restrict__ counter,
    float* __restrict__ out) {
    __shared__ __align__(16) int4 Bbuf[2][512];   // 2 x 8 KB
    __shared__ unsigned int done_s;
    __shared__ float sdata[4];

    const int tid  = threadIdx.x;
    const int lane = tid & 63;
    const int w    = tid >> 6;
    const int lm   = lane & 15;
    const int lg   = lane >> 4;

    const int s  = blockIdx.x / NSEG;       // strip-pair 0..15
    const int q  = blockIdx.x % NSEG;       // segment
    const int L0 = 256 - 8 * s;             // tiles in strip of panel s
    const int cb = (q * TT) / NSEG;
    const int ce = ((q + 1) * TT) / NSEG;

    // staging geometry: thread covers col=tid&31, 32 B at offset (tid>>5)*32
    const int scol = tid & 31;
    const int ssg  = tid >> 5;              // 0..7

    // fragment-read constants
    const int crow = lg >> 1;               // 16B-unit parity within K32
    const int half = (lg & 1) * 8;          // byte half within unit

    long long a[8][4];                      // A panel: 64 rows x 256 K fp8
    floatx4 acc[4][2];
    float rsacc[4][4];
    int4 pf0, pf1;

#pragma unroll
    for (int mi = 0; mi < 4; mi++)
#pragma unroll
        for (int r = 0; r < 4; r++) rsacc[mi][r] = 0.f;

    auto decode = [&](int c, int& panel, int& colbase, int& cloc) {
        if (c < L0) { panel = s;      cloc = c; }
        else        { panel = 31 - s; cloc = c - L0; }
        colbase = panel * 256 + cloc * 32;
    };

    auto loadA = [&](int panel) {
#pragma unroll
        for (int kk = 0; kk < 8; kk++)
#pragma unroll
            for (int mi = 0; mi < 4; mi++)
                a[kk][mi] = *(const long long*)(
                    z + (size_t)(panel * 256 + w * 64 + mi * 16 + lm) * D +
                    kk * 32 + lg * 8);
    };

    auto flushRs = [&](int panel) {
#pragma unroll
        for (int mi = 0; mi < 4; mi++)
#pragma unroll
            for (int r = 0; r < 4; r++) {
                float v = rsacc[mi][r];
                v += __shfl_xor(v, 1); v += __shfl_xor(v, 2);
                v += __shfl_xor(v, 4); v += __shfl_xor(v, 8);
                if (lm == 0)
                    atomicAdd(&rowsum[panel * 256 + w * 64 + mi * 16 + lg * 4 + r], v);
                rsacc[mi][r] = 0.f;
            }
    };

    auto fetch = [&](int colbase) {
        const unsigned char* p = z + (size_t)(colbase + scol) * D + ssg * 32;
        pf0 = *(const int4*)p;
        pf1 = *(const int4*)(p + 16);
    };
    auto writeB = [&](int buf) {
        Bbuf[buf][(ssg * 2 + 0) * 32 + scol] = pf0;
        Bbuf[buf][(ssg * 2 + 1) * 32 + scol] = pf1;
    };

    // ---- prologue ----
    int panel, colbase, cloc;
    decode(cb, panel, colbase, cloc);
    int curpanel = panel;
    fetch(colbase);
    writeB(0);
    loadA(panel);
    __syncthreads();

    for (int c = cb; c < ce; c++) {
        const int buf = (c - cb) & 1;
        decode(c, panel, colbase, cloc);

        const bool hn = (c + 1 < ce);
        if (hn) {
            int npanel, ncolbase, ncloc;
            decode(c + 1, npanel, ncolbase, ncloc);
            fetch(ncolbase);
        }
        if (panel != curpanel) {
            flushRs(curpanel);
            loadA(panel);
            curpanel = panel;
        }

#pragma unroll
        for (int mi = 0; mi < 4; mi++)
#pragma unroll
            for (int ni = 0; ni < 2; ni++)
                acc[mi][ni] = (floatx4){0.f, 0.f, 0.f, 0.f};

        const char* bbase = (const char*)Bbuf[buf];
#pragma unroll
        for (int kk = 0; kk < 8; kk++) {
            long long b0 = *(const long long*)(
                bbase + (((kk * 2 + crow) * 32 + lm) * 16) + half);
            long long b1 = *(const long long*)(
                bbase + (((kk * 2 + crow) * 32 + 16 + lm) * 16) + half);
#pragma unroll
            for (int mi = 0; mi < 4; mi++)
                acc[mi][0] = __builtin_amdgcn_mfma_f32_16x16x32_fp8_fp8(
                    a[kk][mi], b0, acc[mi][0], 0, 0, 0);
#pragma unroll
            for (int mi = 0; mi < 4; mi++)
                acc[mi][1] = __builtin_amdgcn_mfma_f32_16x16x32_fp8_fp8(
                    a[kk][mi], b1, acc[mi][1], 0, 0, 0);
        }

        // ---- epilogue ----
        const bool diagreg = (cloc < 8);
        float cs0 = 0.f, cs1 = 0.f;
        if (diagreg) {
            const int rowb = panel * 256 + w * 64 + lg * 4;
            const int col0 = colbase + lm, col1 = colbase + 16 + lm;
#pragma unroll
            for (int mi = 0; mi < 4; mi++)
#pragma unroll
                for (int r = 0; r < 4; r++) {
                    int grow = rowb + mi * 16 + r;
                    float e0 = (grow == col0) ? 0.f : __expf(2.0f * acc[mi][0][r]);
                    float e1 = (grow == col1) ? 0.f : __expf(2.0f * acc[mi][1][r]);
                    rsacc[mi][r] += e0 + e1;
                }
        } else {
#pragma unroll
            for (int mi = 0; mi < 4; mi++)
#pragma unroll
                for (int r = 0; r < 4; r++) {
                    float e0 = __expf(2.0f * acc[mi][0][r]);
                    float e1 = __expf(2.0f * acc[mi][1][r]);
                    rsacc[mi][r] += e0 + e1;
                    cs0 += e0; cs1 += e1;
                }
            cs0 += __shfl_xor(cs0, 16); cs0 += __shfl_xor(cs0, 32);
            cs1 += __shfl_xor(cs1, 16); cs1 += __shfl_xor(cs1, 32);
            if (lane < 16) {
                atomicAdd(&rowsum[colbase + lane],      cs0);
                atomicAdd(&rowsum[colbase + 16 + lane], cs1);
            }
        }

        if (hn) {
            writeB(buf ^ 1);
            __syncthreads();
        }
    }
    flushRs(curpanel);

    // ---- last-block-done: final loss ----
    __syncthreads();
    if (tid == 0) {
        __threadfence();
        done_s = atomicAdd(counter, 1u);
    }
    __syncthreads();
    if (done_s == (unsigned int)(NBLK2 - 1)) {
        __threadfence();
        float acc_l = 0.f;
#pragma unroll 4
        for (int r = tid; r < NROWS; r += 256) {
            float rsv = __hip_atomic_load(&rowsum[r], __ATOMIC_RELAXED,
                                          __HIP_MEMORY_SCOPE_AGENT);
            acc_l += -2.0f * pos[r] + logf(rsv);
        }
#pragma unroll
        for (int off = 32; off > 0; off >>= 1) acc_l += __shfl_xor(acc_l, off);
        if (lane == 0) sdata[w] = acc_l;
        __syncthreads();
        if (tid == 0)
            out[0] = (sdata[0] + sdata[1] + sdata[2] + sdata[3]) / (float)NROWS;
    }
}

// ---------------------------------------------------------------------------
extern "C" void kernel_launch(void* const* d_in, const int* in_sizes, int n_in,
                              void* d_out, int out_size, void* d_ws, size_t ws_size,
                              hipStream_t stream) {
    const float* xi = (const float*)d_in[0];
    const float* xj = (const float*)d_in[1];
    float* out      = (float*)d_out;

    char* ws        = (char*)d_ws;
    unsigned char* z = (unsigned char*)ws;                    // 2 MiB (fp8)
    float* rowsum   = (float*)(ws + (size_t)NROWS * D);       // 32 KiB
    float* pos      = rowsum + NROWS;                         // 32 KiB
    unsigned int* counter = (unsigned int*)(pos + NROWS);

    norm_pos_kernel<<<B_ROWS / 4, 256, 0, stream>>>(xi, xj, z, pos,
                                                    rowsum, out, counter);
    sim_rowsum_kernel<<<NBLK2, 256, 0, stream>>>(z, rowsum, pos, counter, out);
}